// Round 6
// baseline (1035.861 us; speedup 1.0000x reference)
//
#include <hip/hip_runtime.h>
#include <hip/hip_bf16.h>

#define CDIM 32
#define KCLS 20
#define NBASE 12
#define PPROP 1024
#define TBLW 20   // 18 sem cols (2..19) + binary + count

__device__ __forceinline__ void lds_addf(float* p, float v) {
  __hip_atomic_fetch_add(p, v, __ATOMIC_RELAXED, __HIP_MEMORY_SCOPE_WORKGROUP);
}
__device__ __forceinline__ void glb_addf(float* p, float v) {
  __hip_atomic_fetch_add(p, v, __ATOMIC_RELAXED, __HIP_MEMORY_SCOPE_AGENT);
}

// lane-c value of x broadcast to all lanes (c compile-time const); VALU, not DS
__device__ __forceinline__ float lanebcast(float x, int c) {
  return __builtin_bit_cast(float,
      __builtin_amdgcn_readlane(__builtin_bit_cast(int, x), c));
}

// DPP add step (pure VALU — avoids the per-CU DS pipe that bottlenecked round 4).
// dpp_ctrl must be an immediate -> template parameter (round-5 compile fix).
template <int CTRL>
__device__ __forceinline__ float dpp_add(float x) {
  int s = __builtin_amdgcn_update_dpp(0, __builtin_bit_cast(int, x),
                                      CTRL, 0xf, 0xf, true);
  return x + __builtin_bit_cast(float, s);
}
// sum within each 32-lane half -> lane 31 (half 0) / lane 63 (half 1)
__device__ __forceinline__ float red32(float x) {
  x = dpp_add<0x111>(x);  // row_shr:1
  x = dpp_add<0x112>(x);  // row_shr:2
  x = dpp_add<0x114>(x);  // row_shr:4
  x = dpp_add<0x118>(x);  // row_shr:8  -> lane15/31/47/63 = row sums
  x = dpp_add<0x142>(x);  // row_bcast:15 -> lane31 = sum(0..31), lane63 = sum(32..63)
  return x;
}

// ---------------- scores: open-vocab renormalized softmax-gate ----------------
__global__ void k_scores(const float* __restrict__ sem, const float* __restrict__ bin,
                         float* __restrict__ out, int n) {
  int stride = gridDim.x * blockDim.x;
  for (int i = blockIdx.x * blockDim.x + threadIdx.x; i < n; i += stride) {
    const float4* r = reinterpret_cast<const float4*>(sem + (size_t)i * KCLS);
    float s[KCLS];
    float4 v;
    v = r[0]; s[0]=v.x; s[1]=v.y; s[2]=v.z; s[3]=v.w;
    v = r[1]; s[4]=v.x; s[5]=v.y; s[6]=v.z; s[7]=v.w;
    v = r[2]; s[8]=v.x; s[9]=v.y; s[10]=v.z; s[11]=v.w;
    v = r[3]; s[12]=v.x; s[13]=v.y; s[14]=v.z; s[15]=v.w;
    v = r[4]; s[16]=v.x; s[17]=v.y; s[18]=v.z; s[19]=v.w;

    float m12 = s[0];
#pragma unroll
    for (int k = 1; k < NBASE; k++) m12 = fmaxf(m12, s[k]);
    float sum12 = 0.f;
#pragma unroll
    for (int k = 0; k < NBASE; k++) { s[k] = __expf(s[k] - m12); sum12 += s[k]; }

    float m8 = s[NBASE];
#pragma unroll
    for (int k = NBASE + 1; k < KCLS; k++) m8 = fmaxf(m8, s[k]);
    float sum8 = 0.f;
#pragma unroll
    for (int k = NBASE; k < KCLS; k++) { s[k] = __expf(s[k] - m8); sum8 += s[k]; }

    float sig = 1.f / (1.f + __expf(-bin[i]));
    // analytic: renormalization denominator == 1, fold gate/softmax-denoms
    float cb = sig / sum12;
    float cn = (1.f - sig) / sum8;
#pragma unroll
    for (int k = 0; k < NBASE; k++) s[k] *= cb;
#pragma unroll
    for (int k = NBASE; k < KCLS; k++) s[k] *= cn;

    float4* o = reinterpret_cast<float4*>(out + (size_t)i * KCLS);
    o[0] = make_float4(s[0], s[1], s[2], s[3]);
    o[1] = make_float4(s[4], s[5], s[6], s[7]);
    o[2] = make_float4(s[8], s[9], s[10], s[11]);
    o[3] = make_float4(s[12], s[13], s[14], s[15]);
    o[4] = make_float4(s[16], s[17], s[18], s[19]);
  }
}

// ---------------- proposal scatter-mean accumulation ----------------
__global__ __launch_bounds__(512) void k_scatter(const float* __restrict__ sem,
    const float* __restrict__ bin, const int* __restrict__ pidx,
    const int* __restrict__ pid, float* __restrict__ acc, int m) {
  __shared__ float tbl[PPROP * TBLW];  // 80 KiB
  for (int t = threadIdx.x; t < PPROP * TBLW; t += blockDim.x) tbl[t] = 0.f;
  __syncthreads();

  int stride = gridDim.x * blockDim.x;
  for (int i = blockIdx.x * blockDim.x + threadIdx.x; i < m; i += stride) {
    int q = pidx[i];
    int p = pid[i];
    const float* row = sem + (size_t)q * KCLS;
    float2 a  = *reinterpret_cast<const float2*>(row + 2);
    float4 c0 = *reinterpret_cast<const float4*>(row + 4);
    float4 c1 = *reinterpret_cast<const float4*>(row + 8);
    float4 c2 = *reinterpret_cast<const float4*>(row + 12);
    float4 c3 = *reinterpret_cast<const float4*>(row + 16);
    float bv = bin[q];
    float* t = tbl + p * TBLW;
    lds_addf(t + 0, a.x);  lds_addf(t + 1, a.y);
    lds_addf(t + 2, c0.x); lds_addf(t + 3, c0.y); lds_addf(t + 4, c0.z); lds_addf(t + 5, c0.w);
    lds_addf(t + 6, c1.x); lds_addf(t + 7, c1.y); lds_addf(t + 8, c1.z); lds_addf(t + 9, c1.w);
    lds_addf(t +10, c2.x); lds_addf(t +11, c2.y); lds_addf(t +12, c2.z); lds_addf(t +13, c2.w);
    lds_addf(t +14, c3.x); lds_addf(t +15, c3.y); lds_addf(t +16, c3.z); lds_addf(t +17, c3.w);
    lds_addf(t +18, bv);
    lds_addf(t +19, 1.f);
  }
  __syncthreads();
  for (int t = threadIdx.x; t < PPROP * TBLW; t += blockDim.x) {
    float v = tbl[t];
    if (v != 0.f) glb_addf(acc + t, v);
  }
}

// ---------------- mask/iou heads + BN statistics over h1 = feats@W1+b1 ----------------
// Wave-per-point: lanes 0-31 own Wm1 columns, lanes 32-63 own W1 columns (in VGPRs,
// loaded once). f broadcast via v_readlane (VALU). Zero DS in the inner loop —
// round-4 lesson: LDS-sourced FMA operands oversubscribe the per-CU DS pipe 4x.
__global__ __launch_bounds__(256, 4) void k_heads(const float* __restrict__ feats,
    const float* __restrict__ W1,  const float* __restrict__ b1,
    const float* __restrict__ Wm1, const float* __restrict__ bm1,
    const float* __restrict__ Wm2, const float* __restrict__ bm2,
    const float* __restrict__ Wi,  const float* __restrict__ bi,
    float* __restrict__ mask_out, float* __restrict__ iou_out,
    float* __restrict__ stats, int n) {
  __shared__ float red[2 * CDIM];

  int t = threadIdx.x;
  int lane = t & 63;
  int col  = lane & 31;
  int half = lane >> 5;

  const float* Wsel = half ? W1 : Wm1;
  float w[CDIM];
#pragma unroll
  for (int c = 0; c < CDIM; c++) w[c] = Wsel[c * CDIM + col];
  float breg = half ? b1[col] : bm1[col];
  float mreg = half ? Wi[col] : Wm2[col];
  float bm2v = bm2[0], biv = bi[0];

  float hs = 0.f, hq = 0.f;   // per-column BN stats (valid in half 1 lanes)

  int wave   = (blockIdx.x * blockDim.x + t) >> 6;
  int nwaves = (gridDim.x * blockDim.x) >> 6;

  for (int p = wave; p < n; p += nwaves) {
    float f_v = feats[(size_t)p * CDIM + col];   // both halves: 128B coalesced

    float a0 = breg, a1 = 0.f, a2 = 0.f, a3 = 0.f;
#pragma unroll
    for (int c = 0; c < CDIM; c += 4) {
      a0 = fmaf(lanebcast(f_v, c),     w[c],     a0);
      a1 = fmaf(lanebcast(f_v, c + 1), w[c + 1], a1);
      a2 = fmaf(lanebcast(f_v, c + 2), w[c + 2], a2);
      a3 = fmaf(lanebcast(f_v, c + 3), w[c + 3], a3);
    }
    float a = (a0 + a1) + (a2 + a3);   // half0: mask hidden_col; half1: h1_col

    float r = fmaxf(a, 0.f);
    float val = half ? f_v : r;        // half0: relu(hidden)*Wm2, half1: f*Wi
    float tmp = red32(val * mreg);
    if (lane == 31) mask_out[p] = tmp + bm2v;
    if (lane == 63) iou_out[p]  = tmp + biv;

    hs += a;                            // garbage in half0, masked at flush
    hq = fmaf(a, a, hq);
  }

  __syncthreads();
  for (int q = t; q < 2 * CDIM; q += blockDim.x) red[q] = 0.f;
  __syncthreads();
  if (half) { lds_addf(&red[col], hs); lds_addf(&red[CDIM + col], hq); }
  __syncthreads();
  for (int q = t; q < 2 * CDIM; q += blockDim.x) glb_addf(&stats[q], red[q]);
}

// ---------------- tiny: fold BN stats + b1 into scale/shift ----------------
__global__ void k_bnprep(const float* __restrict__ stats,
                         const float* __restrict__ g1, const float* __restrict__ be1,
                         const float* __restrict__ b1,
                         float* __restrict__ bnsc, float* __restrict__ bntc, float invN) {
  int j = threadIdx.x;
  if (j < CDIM) {
    float mu  = stats[j] * invN;
    float var = stats[CDIM + j] * invN - mu * mu;
    float isd = rsqrtf(var + 1e-4f);
    float sc = g1[j] * isd;
    bnsc[j] = sc;
    // y = (a + b1 - mu)*sc + be1, a = f@W1 (bias folded so k_offsets accumulates from 0)
    bntc[j] = be1[j] + (b1[j] - mu) * sc;
  }
}

// ---------------- pt_offsets: Linear->BN(precomputed sc/tc)->ReLU->Linear ----------------
// Same wave-per-point structure; both halves compute identical h1 column so the
// x/y reductions ride one red32 (lane31=ox, lane63=oy) and z a second.
__global__ __launch_bounds__(256, 4) void k_offsets(const float* __restrict__ feats,
    const float* __restrict__ W1,
    const float* __restrict__ W2, const float* __restrict__ b2,
    const float* __restrict__ bnsc, const float* __restrict__ bntc,
    float* __restrict__ out_off, int n) {
  int t = threadIdx.x;
  int lane = t & 63;
  int col  = lane & 31;
  int half = lane >> 5;

  float w[CDIM];
#pragma unroll
  for (int c = 0; c < CDIM; c++) w[c] = W1[c * CDIM + col];
  float scv = bnsc[col], tcv = bntc[col];
  float wxy = half ? W2[col * 3 + 1] : W2[col * 3 + 0];
  float wz  = W2[col * 3 + 2];
  float b2x = b2[0], b2y = b2[1], b2z = b2[2];

  int wave   = (blockIdx.x * blockDim.x + t) >> 6;
  int nwaves = (gridDim.x * blockDim.x) >> 6;

  for (int p = wave; p < n; p += nwaves) {
    float f_v = feats[(size_t)p * CDIM + col];

    float a0 = 0.f, a1 = 0.f, a2 = 0.f, a3 = 0.f;
#pragma unroll
    for (int c = 0; c < CDIM; c += 4) {
      a0 = fmaf(lanebcast(f_v, c),     w[c],     a0);
      a1 = fmaf(lanebcast(f_v, c + 1), w[c + 1], a1);
      a2 = fmaf(lanebcast(f_v, c + 2), w[c + 2], a2);
      a3 = fmaf(lanebcast(f_v, c + 3), w[c + 3], a3);
    }
    float a = (a0 + a1) + (a2 + a3);           // h1_col (same in both halves)
    float y = fmaxf(fmaf(a, scv, tcv), 0.f);   // BN + ReLU

    float t1 = red32(y * wxy);   // lane31 = ox, lane63 = oy
    float t2 = red32(y * wz);    // lane31 = oz (lane63 = oz as well)
    if (lane == 31) {
      size_t o = (size_t)p * 3;
      out_off[o]     = t1 + b2x;
      out_off[o + 2] = t2 + b2z;
    }
    if (lane == 63) out_off[(size_t)p * 3 + 1] = t1 + b2y;
  }
}

// ---------------- finalize proposal means ----------------
__global__ void k_finalize(const float* __restrict__ acc,
                           float* __restrict__ psem, float* __restrict__ pbin) {
  int p = blockIdx.x * blockDim.x + threadIdx.x;
  if (p < PPROP) {
    const float* t = acc + p * TBLW;
    float cnt = fmaxf(t[19], 1.f);
    float r = 1.f / cnt;
#pragma unroll
    for (int c = 0; c < 18; c++) psem[p * 18 + c] = t[c] * r;
    pbin[p] = t[18] * r;
  }
}

extern "C" void kernel_launch(void* const* d_in, const int* in_sizes, int n_in,
                              void* d_out, int out_size, void* d_ws, size_t ws_size,
                              hipStream_t stream) {
  const float* feats = (const float*)d_in[0];
  const float* sem   = (const float*)d_in[1];
  const float* bin   = (const float*)d_in[2];
  const int*   pidx  = (const int*)d_in[3];
  const int*   pid   = (const int*)d_in[4];
  const float* W1  = (const float*)d_in[5];
  const float* b1  = (const float*)d_in[6];
  const float* g1  = (const float*)d_in[7];
  const float* be1 = (const float*)d_in[8];
  const float* W2  = (const float*)d_in[9];
  const float* b2  = (const float*)d_in[10];
  const float* Wm1 = (const float*)d_in[11];
  const float* bm1 = (const float*)d_in[12];
  const float* Wm2 = (const float*)d_in[13];
  const float* bm2 = (const float*)d_in[14];
  const float* Wi  = (const float*)d_in[15];
  const float* bi  = (const float*)d_in[16];

  int n = in_sizes[2];   // binary_scores is (N,1)
  int m = in_sizes[3];   // memberships

  float* out = (float*)d_out;
  float* o_scores = out;
  float* o_off  = out + (size_t)n * KCLS;
  float* o_psem = o_off + (size_t)n * 3;
  float* o_pbin = o_psem + (size_t)PPROP * 18;
  float* o_mask = o_pbin + PPROP;
  float* o_iou  = o_mask + n;

  float* stats = (float*)d_ws;         // 64 floats: sum[32], sumsq[32]
  float* bnsc  = stats + 2 * CDIM;     // 32
  float* bntc  = bnsc + CDIM;          // 32
  float* acc   = bntc + CDIM;          // P*TBLW floats

  // zero accumulators every launch (harness does not re-poison between replays)
  (void)hipMemsetAsync(d_ws, 0, (4 * CDIM + PPROP * TBLW) * sizeof(float), stream);

  k_scores  <<<2048, 256, 0, stream>>>(sem, bin, o_scores, n);
  // run scatter right after scores so semantic_scores is L3-resident for the gather
  k_scatter <<<256, 512, 0, stream>>>(sem, bin, pidx, pid, acc, m);
  k_heads   <<<2048, 256, 0, stream>>>(feats, W1, b1, Wm1, bm1, Wm2, bm2, Wi, bi,
                                       o_mask, o_iou, stats, n);
  k_bnprep  <<<1, 64, 0, stream>>>(stats, g1, be1, b1, bnsc, bntc, 1.0f / (float)n);
  k_offsets <<<2048, 256, 0, stream>>>(feats, W1, W2, b2, bnsc, bntc, o_off, n);
  k_finalize<<<4, 256, 0, stream>>>(acc, o_psem, o_pbin);
}

// Round 7
// 455.147 us; speedup vs baseline: 2.2759x; 2.2759x over previous
//
#include <hip/hip_runtime.h>
#include <hip/hip_bf16.h>

#define CDIM 32
#define KCLS 20
#define NBASE 12
#define PPROP 1024
#define TBLW 20   // 18 sem cols (2..19) + binary + count

typedef __attribute__((ext_vector_type(8))) short bf16x8;
typedef __attribute__((ext_vector_type(4))) float f32x4;

__device__ __forceinline__ void lds_addf(float* p, float v) {
  __hip_atomic_fetch_add(p, v, __ATOMIC_RELAXED, __HIP_MEMORY_SCOPE_WORKGROUP);
}
__device__ __forceinline__ void glb_addf(float* p, float v) {
  __hip_atomic_fetch_add(p, v, __ATOMIC_RELAXED, __HIP_MEMORY_SCOPE_AGENT);
}

// f32 -> bf16 (round-to-nearest-even), bit pattern in a short
__device__ __forceinline__ short f2bf(float x) {
  unsigned u = __builtin_bit_cast(unsigned, x);
  unsigned r = (u + 0x7fffu + ((u >> 16) & 1u)) >> 16;
  return (short)r;
}

// DPP add step; ctrl immediate via template (round-5 lesson)
template <int CTRL>
__device__ __forceinline__ float dpp_add(float x) {
  int s = __builtin_amdgcn_update_dpp(0, __builtin_bit_cast(int, x),
                                      CTRL, 0xf, 0xf, true);
  return x + __builtin_bit_cast(float, s);
}
// sum across each 16-lane DPP row -> lanes 15/31/47/63 hold the row total
__device__ __forceinline__ float red16(float x) {
  x = dpp_add<0x111>(x);  // row_shr:1
  x = dpp_add<0x112>(x);  // row_shr:2
  x = dpp_add<0x114>(x);  // row_shr:4
  x = dpp_add<0x118>(x);  // row_shr:8
  return x;
}
// sum within each 32-lane half -> lane 31 / lane 63 (for k_scores-free kernels unused)

// B-frag for mfma_f32_16x16x32_bf16 from row-major [K=32][N=32] weight matrix.
// lane: n = (lane&15)+colOff, k = (lane>>4)*8 + e (8 k-contiguous elements)
__device__ __forceinline__ bf16x8 make_bfrag(const float* __restrict__ W,
                                             int lane, int colOff) {
  int n = (lane & 15) + colOff;
  int kb = (lane >> 4) * 8;
  bf16x8 b;
#pragma unroll
  for (int e = 0; e < 8; e++) b[e] = f2bf(W[(kb + e) * CDIM + n]);
  return b;
}

// ---------------- scores: open-vocab renormalized softmax-gate ----------------
__global__ void k_scores(const float* __restrict__ sem, const float* __restrict__ bin,
                         float* __restrict__ out, int n) {
  int stride = gridDim.x * blockDim.x;
  for (int i = blockIdx.x * blockDim.x + threadIdx.x; i < n; i += stride) {
    const float4* r = reinterpret_cast<const float4*>(sem + (size_t)i * KCLS);
    float s[KCLS];
    float4 v;
    v = r[0]; s[0]=v.x; s[1]=v.y; s[2]=v.z; s[3]=v.w;
    v = r[1]; s[4]=v.x; s[5]=v.y; s[6]=v.z; s[7]=v.w;
    v = r[2]; s[8]=v.x; s[9]=v.y; s[10]=v.z; s[11]=v.w;
    v = r[3]; s[12]=v.x; s[13]=v.y; s[14]=v.z; s[15]=v.w;
    v = r[4]; s[16]=v.x; s[17]=v.y; s[18]=v.z; s[19]=v.w;

    float m12 = s[0];
#pragma unroll
    for (int k = 1; k < NBASE; k++) m12 = fmaxf(m12, s[k]);
    float sum12 = 0.f;
#pragma unroll
    for (int k = 0; k < NBASE; k++) { s[k] = __expf(s[k] - m12); sum12 += s[k]; }

    float m8 = s[NBASE];
#pragma unroll
    for (int k = NBASE + 1; k < KCLS; k++) m8 = fmaxf(m8, s[k]);
    float sum8 = 0.f;
#pragma unroll
    for (int k = NBASE; k < KCLS; k++) { s[k] = __expf(s[k] - m8); sum8 += s[k]; }

    float sig = 1.f / (1.f + __expf(-bin[i]));
    // analytic: renormalization denominator == 1, fold gate/softmax-denoms
    float cb = sig / sum12;
    float cn = (1.f - sig) / sum8;
#pragma unroll
    for (int k = 0; k < NBASE; k++) s[k] *= cb;
#pragma unroll
    for (int k = NBASE; k < KCLS; k++) s[k] *= cn;

    float4* o = reinterpret_cast<float4*>(out + (size_t)i * KCLS);
    o[0] = make_float4(s[0], s[1], s[2], s[3]);
    o[1] = make_float4(s[4], s[5], s[6], s[7]);
    o[2] = make_float4(s[8], s[9], s[10], s[11]);
    o[3] = make_float4(s[12], s[13], s[14], s[15]);
    o[4] = make_float4(s[16], s[17], s[18], s[19]);
  }
}

// ---------------- proposal scatter-mean accumulation ----------------
__global__ __launch_bounds__(512) void k_scatter(const float* __restrict__ sem,
    const float* __restrict__ bin, const int* __restrict__ pidx,
    const int* __restrict__ pid, float* __restrict__ acc, int m) {
  __shared__ float tbl[PPROP * TBLW];  // 80 KiB
  for (int t = threadIdx.x; t < PPROP * TBLW; t += blockDim.x) tbl[t] = 0.f;
  __syncthreads();

  int stride = gridDim.x * blockDim.x;
  for (int i = blockIdx.x * blockDim.x + threadIdx.x; i < m; i += stride) {
    int q = pidx[i];
    int p = pid[i];
    const float* row = sem + (size_t)q * KCLS;
    float2 a  = *reinterpret_cast<const float2*>(row + 2);
    float4 c0 = *reinterpret_cast<const float4*>(row + 4);
    float4 c1 = *reinterpret_cast<const float4*>(row + 8);
    float4 c2 = *reinterpret_cast<const float4*>(row + 12);
    float4 c3 = *reinterpret_cast<const float4*>(row + 16);
    float bv = bin[q];
    float* t = tbl + p * TBLW;
    lds_addf(t + 0, a.x);  lds_addf(t + 1, a.y);
    lds_addf(t + 2, c0.x); lds_addf(t + 3, c0.y); lds_addf(t + 4, c0.z); lds_addf(t + 5, c0.w);
    lds_addf(t + 6, c1.x); lds_addf(t + 7, c1.y); lds_addf(t + 8, c1.z); lds_addf(t + 9, c1.w);
    lds_addf(t +10, c2.x); lds_addf(t +11, c2.y); lds_addf(t +12, c2.z); lds_addf(t +13, c2.w);
    lds_addf(t +14, c3.x); lds_addf(t +15, c3.y); lds_addf(t +16, c3.z); lds_addf(t +17, c3.w);
    lds_addf(t +18, bv);
    lds_addf(t +19, 1.f);
  }
  __syncthreads();
  for (int t = threadIdx.x; t < PPROP * TBLW; t += blockDim.x) {
    float v = tbl[t];
    if (v != 0.f) glb_addf(acc + t, v);
  }
}

// ---------------- heads via MFMA: mask, iou, BN stats over h1=f@W1 ----------------
// Wave handles 16 points. A = f tile (16x32, bf16), B = weight frags.
// C/D layout (HW-verified): col=lane&15, row=(lane>>4)*4+reg.
__global__ __launch_bounds__(256, 4) void k_heads_m(const float* __restrict__ feats,
    const float* __restrict__ W1,
    const float* __restrict__ Wm1, const float* __restrict__ bm1,
    const float* __restrict__ Wm2, const float* __restrict__ bm2,
    const float* __restrict__ Wi,  const float* __restrict__ bi,
    float* __restrict__ mask_out, float* __restrict__ iou_out,
    float* __restrict__ stats, int n) {
  __shared__ float red[4 * 16 + 48];  // 64 floats: S[32], Q[32]
  int t = threadIdx.x;
  int lane = t & 63;
  int nn = lane & 15;
  int grp = lane >> 4;

  bf16x8 bWm0 = make_bfrag(Wm1, lane, 0);
  bf16x8 bWm1f = make_bfrag(Wm1, lane, 16);
  bf16x8 bW10 = make_bfrag(W1, lane, 0);
  bf16x8 bW11 = make_bfrag(W1, lane, 16);
  bf16x8 bWi;
  {
    int kb = grp * 8;
#pragma unroll
    for (int e = 0; e < 8; e++) bWi[e] = (nn == 0) ? f2bf(Wi[kb + e]) : (short)0;
  }
  float bm1a = bm1[nn], bm1b = bm1[nn + 16];
  float wm2a = Wm2[nn], wm2b = Wm2[nn + 16];
  float bm2v = bm2[0], biv = bi[0];

  float hs0 = 0.f, hs1 = 0.f, hq0 = 0.f, hq1 = 0.f;

  int wave   = (blockIdx.x * blockDim.x + t) >> 6;
  int nwaves = (gridDim.x * blockDim.x) >> 6;
  int ntiles = (n + 15) >> 4;

  for (int tile = wave; tile < ntiles; tile += nwaves) {
    int p0 = tile << 4;
    int row = p0 + nn;
    bool rv = row < n;
    const float4* fr = reinterpret_cast<const float4*>(
        feats + (size_t)(rv ? row : (n - 1)) * CDIM + grp * 8);
    float4 v0 = fr[0], v1 = fr[1];
    bf16x8 a;
    if (rv) {
      a[0] = f2bf(v0.x); a[1] = f2bf(v0.y); a[2] = f2bf(v0.z); a[3] = f2bf(v0.w);
      a[4] = f2bf(v1.x); a[5] = f2bf(v1.y); a[6] = f2bf(v1.z); a[7] = f2bf(v1.w);
    } else {
#pragma unroll
      for (int e = 0; e < 8; e++) a[e] = 0;
    }

    f32x4 am0, am1, ah0, ah1, ai;
#pragma unroll
    for (int r = 0; r < 4; r++) { am0[r] = bm1a; am1[r] = bm1b; ah0[r] = 0.f; ah1[r] = 0.f; ai[r] = 0.f; }

    am0 = __builtin_amdgcn_mfma_f32_16x16x32_bf16(a, bWm0,  am0, 0, 0, 0);
    am1 = __builtin_amdgcn_mfma_f32_16x16x32_bf16(a, bWm1f, am1, 0, 0, 0);
    ah0 = __builtin_amdgcn_mfma_f32_16x16x32_bf16(a, bW10,  ah0, 0, 0, 0);
    ah1 = __builtin_amdgcn_mfma_f32_16x16x32_bf16(a, bW11,  ah1, 0, 0, 0);
    ai  = __builtin_amdgcn_mfma_f32_16x16x32_bf16(a, bWi,   ai,  0, 0, 0);

    // mask: per lane t_r = relu(hid[m][n])*Wm2[n] + relu(hid[m][n+16])*Wm2[n+16]
    float t0 = fmaxf(am0[0], 0.f) * wm2a + fmaxf(am1[0], 0.f) * wm2b;
    float t1 = fmaxf(am0[1], 0.f) * wm2a + fmaxf(am1[1], 0.f) * wm2b;
    float t2 = fmaxf(am0[2], 0.f) * wm2a + fmaxf(am1[2], 0.f) * wm2b;
    float t3 = fmaxf(am0[3], 0.f) * wm2a + fmaxf(am1[3], 0.f) * wm2b;
    t0 = red16(t0); t1 = red16(t1); t2 = red16(t2); t3 = red16(t3);

    if (p0 + 16 <= n) {
      if (nn == 15) {
        *reinterpret_cast<float4*>(mask_out + p0 + grp * 4) =
            make_float4(t0 + bm2v, t1 + bm2v, t2 + bm2v, t3 + bm2v);
      }
      if (nn == 0) {
        *reinterpret_cast<float4*>(iou_out + p0 + grp * 4) =
            make_float4(ai[0] + biv, ai[1] + biv, ai[2] + biv, ai[3] + biv);
      }
    } else {
      if (nn == 15) {
        float tv[4] = {t0, t1, t2, t3};
#pragma unroll
        for (int r = 0; r < 4; r++) {
          int p = p0 + grp * 4 + r;
          if (p < n) mask_out[p] = tv[r] + bm2v;
        }
      }
      if (nn == 0) {
#pragma unroll
        for (int r = 0; r < 4; r++) {
          int p = p0 + grp * 4 + r;
          if (p < n) iou_out[p] = ai[r] + biv;
        }
      }
    }

    // BN stats (bias-free h1; invalid rows contribute exact 0)
#pragma unroll
    for (int r = 0; r < 4; r++) {
      hs0 += ah0[r]; hq0 = fmaf(ah0[r], ah0[r], hq0);
      hs1 += ah1[r]; hq1 = fmaf(ah1[r], ah1[r], hq1);
    }
  }

  __syncthreads();
  for (int q = t; q < 64; q += blockDim.x) red[q] = 0.f;
  __syncthreads();
  lds_addf(&red[nn], hs0);       lds_addf(&red[nn + 16], hs1);
  lds_addf(&red[32 + nn], hq0);  lds_addf(&red[48 + nn], hq1);
  __syncthreads();
  for (int q = t; q < 64; q += blockDim.x) glb_addf(&stats[q], red[q]);
}

// ---------------- tiny: fold BN stats into scale/shift ----------------
// stats hold S=sum(f@W1), Q=sum((f@W1)^2); var is shift-invariant so b1 cancels,
// and tc = be1 - mean_x*sc makes (h_noBias*sc + tc) == BN(h_full).
__global__ void k_bnprep(const float* __restrict__ stats,
                         const float* __restrict__ g1, const float* __restrict__ be1,
                         float* __restrict__ bnsc, float* __restrict__ bntc, float invN) {
  int j = threadIdx.x;
  if (j < CDIM) {
    float mean = stats[j] * invN;
    float var  = stats[CDIM + j] * invN - mean * mean;
    float sc = g1[j] * rsqrtf(var + 1e-4f);
    bnsc[j] = sc;
    bntc[j] = be1[j] - mean * sc;
  }
}

// ---------------- pt_offsets via MFMA: Linear->BN->ReLU->Linear ----------------
__global__ __launch_bounds__(256, 4) void k_offsets_m(const float* __restrict__ feats,
    const float* __restrict__ W1,
    const float* __restrict__ W2, const float* __restrict__ b2,
    const float* __restrict__ bnsc, const float* __restrict__ bntc,
    float* __restrict__ out_off, int n) {
  int t = threadIdx.x;
  int lane = t & 63;
  int nn = lane & 15;
  int grp = lane >> 4;

  bf16x8 bW10 = make_bfrag(W1, lane, 0);
  bf16x8 bW11 = make_bfrag(W1, lane, 16);
  float scA = bnsc[nn], scB = bnsc[nn + 16];
  float tcA = bntc[nn], tcB = bntc[nn + 16];
  float wxA = W2[nn * 3 + 0], wxB = W2[(nn + 16) * 3 + 0];
  float wyA = W2[nn * 3 + 1], wyB = W2[(nn + 16) * 3 + 1];
  float wzA = W2[nn * 3 + 2], wzB = W2[(nn + 16) * 3 + 2];
  float b2x = b2[0], b2y = b2[1], b2z = b2[2];

  int wave   = (blockIdx.x * blockDim.x + t) >> 6;
  int nwaves = (gridDim.x * blockDim.x) >> 6;
  int ntiles = (n + 15) >> 4;

  for (int tile = wave; tile < ntiles; tile += nwaves) {
    int p0 = tile << 4;
    int row = p0 + nn;
    bool rv = row < n;
    const float4* fr = reinterpret_cast<const float4*>(
        feats + (size_t)(rv ? row : (n - 1)) * CDIM + grp * 8);
    float4 v0 = fr[0], v1 = fr[1];
    bf16x8 a;
    if (rv) {
      a[0] = f2bf(v0.x); a[1] = f2bf(v0.y); a[2] = f2bf(v0.z); a[3] = f2bf(v0.w);
      a[4] = f2bf(v1.x); a[5] = f2bf(v1.y); a[6] = f2bf(v1.z); a[7] = f2bf(v1.w);
    } else {
#pragma unroll
      for (int e = 0; e < 8; e++) a[e] = 0;
    }

    f32x4 ah0 = {0.f, 0.f, 0.f, 0.f}, ah1 = {0.f, 0.f, 0.f, 0.f};
    ah0 = __builtin_amdgcn_mfma_f32_16x16x32_bf16(a, bW10, ah0, 0, 0, 0);
    ah1 = __builtin_amdgcn_mfma_f32_16x16x32_bf16(a, bW11, ah1, 0, 0, 0);

    float tx[4], ty[4], tz[4];
#pragma unroll
    for (int r = 0; r < 4; r++) {
      float y0 = fmaxf(fmaf(ah0[r], scA, tcA), 0.f);
      float y1 = fmaxf(fmaf(ah1[r], scB, tcB), 0.f);
      tx[r] = red16(y0 * wxA + y1 * wxB);
      ty[r] = red16(y0 * wyA + y1 * wyB);
      tz[r] = red16(y0 * wzA + y1 * wzB);
    }

    if (nn == 15) {
      int pbase = p0 + grp * 4;
      if (pbase + 4 <= n) {
        float4* o = reinterpret_cast<float4*>(out_off + (size_t)pbase * 3);
        o[0] = make_float4(tx[0] + b2x, ty[0] + b2y, tz[0] + b2z, tx[1] + b2x);
        o[1] = make_float4(ty[1] + b2y, tz[1] + b2z, tx[2] + b2x, ty[2] + b2y);
        o[2] = make_float4(tz[2] + b2z, tx[3] + b2x, ty[3] + b2y, tz[3] + b2z);
      } else {
#pragma unroll
        for (int r = 0; r < 4; r++) {
          int p = pbase + r;
          if (p < n) {
            out_off[(size_t)p * 3 + 0] = tx[r] + b2x;
            out_off[(size_t)p * 3 + 1] = ty[r] + b2y;
            out_off[(size_t)p * 3 + 2] = tz[r] + b2z;
          }
        }
      }
    }
  }
}

// ---------------- finalize proposal means ----------------
__global__ void k_finalize(const float* __restrict__ acc,
                           float* __restrict__ psem, float* __restrict__ pbin) {
  int p = blockIdx.x * blockDim.x + threadIdx.x;
  if (p < PPROP) {
    const float* t = acc + p * TBLW;
    float cnt = fmaxf(t[19], 1.f);
    float r = 1.f / cnt;
#pragma unroll
    for (int c = 0; c < 18; c++) psem[p * 18 + c] = t[c] * r;
    pbin[p] = t[18] * r;
  }
}

extern "C" void kernel_launch(void* const* d_in, const int* in_sizes, int n_in,
                              void* d_out, int out_size, void* d_ws, size_t ws_size,
                              hipStream_t stream) {
  const float* feats = (const float*)d_in[0];
  const float* sem   = (const float*)d_in[1];
  const float* bin   = (const float*)d_in[2];
  const int*   pidx  = (const int*)d_in[3];
  const int*   pid   = (const int*)d_in[4];
  const float* W1  = (const float*)d_in[5];
  // b1 (d_in[6]) cancels analytically: BN var is shift-invariant, mean shift folds
  const float* g1  = (const float*)d_in[7];
  const float* be1 = (const float*)d_in[8];
  const float* W2  = (const float*)d_in[9];
  const float* b2  = (const float*)d_in[10];
  const float* Wm1 = (const float*)d_in[11];
  const float* bm1 = (const float*)d_in[12];
  const float* Wm2 = (const float*)d_in[13];
  const float* bm2 = (const float*)d_in[14];
  const float* Wi  = (const float*)d_in[15];
  const float* bi  = (const float*)d_in[16];

  int n = in_sizes[2];   // binary_scores is (N,1)
  int m = in_sizes[3];   // memberships

  float* out = (float*)d_out;
  float* o_scores = out;
  float* o_off  = out + (size_t)n * KCLS;
  float* o_psem = o_off + (size_t)n * 3;
  float* o_pbin = o_psem + (size_t)PPROP * 18;
  float* o_mask = o_pbin + PPROP;
  float* o_iou  = o_mask + n;

  float* stats = (float*)d_ws;         // 64 floats: S[32], Q[32]
  float* bnsc  = stats + 2 * CDIM;     // 32
  float* bntc  = bnsc + CDIM;          // 32
  float* acc   = bntc + CDIM;          // P*TBLW floats

  // zero accumulators every launch (harness does not re-poison between replays)
  (void)hipMemsetAsync(d_ws, 0, (4 * CDIM + PPROP * TBLW) * sizeof(float), stream);

  k_scores  <<<2048, 256, 0, stream>>>(sem, bin, o_scores, n);
  // run scatter right after scores so semantic_scores is L3-resident for the gather
  k_scatter <<<256, 512, 0, stream>>>(sem, bin, pidx, pid, acc, m);
  k_heads_m <<<2048, 256, 0, stream>>>(feats, W1, Wm1, bm1, Wm2, bm2, Wi, bi,
                                       o_mask, o_iou, stats, n);
  k_bnprep  <<<1, 64, 0, stream>>>(stats, g1, be1, bnsc, bntc, 1.0f / (float)n);
  k_offsets_m<<<2048, 256, 0, stream>>>(feats, W1, W2, b2, bnsc, bntc, o_off, n);
  k_finalize<<<4, 256, 0, stream>>>(acc, o_psem, o_pbin);
}